// Round 7
// baseline (408.448 us; speedup 1.0000x reference)
//
#include <hip/hip_runtime.h>
#include <math.h>

// PixelQueryNet fused kernel, v6.
// Per low-res cell (b,i,j): MLP 4->64->64->64->64->3 (leaky 0.01, tanh) on the
// 64 pixels of its 8x8 tile; weights from lr_params[b,c,i,j] (channel stride
// PLANE=4096 floats).
//
// Block = 128 threads = 2 cells(j) x 8 pixel-rows(pg) x 8 co-blocks(cob);
// y[8co][8px] accumulators in registers. LDS ~36.9 KB -> 4 blocks/CU
// (8 waves/CU from 4 INDEPENDENT blocks -> barrier gaps overlap).
// 53 barriers/block (256-ch weight tiles) vs R6's 102.
// Grid = 4096; siblings n,n+8,..,n+56 (same XCD under %8 round-robin) take
// the eight 8B j-pairs of each 64B weight line -> L2 sharing, HBM ideal.
//
// Weight tiles [j][WROW=260] double-buffered; per-(ci,q) wave read touches 8
// distinct bank-quads covering all 32 banks exactly once (conflict-free).
// Activations: two unpadded planes (k0..3 / k4..7), word = ci*64 + 4*(lane&15)
// -> 16 distinct addrs, 4-way broadcast, 2-way banks (free).
// One raw s_barrier + lgkmcnt(0) per tile; 2-deep global prefetch in flight.

static constexpr int PLANE = 4096;
static constexpr int NPAR  = 12995;
static constexpr int NT    = 53;     // 2 (L0 bias+w) + 3*17 (hidden)
static constexpr int WROW  = 260;    // words per j-row in weight tile
static constexpr int AHI   = 4096;   // word offset of the k4..7 plane

__device__ __forceinline__ float leaky(float v) { return fmaxf(v, 0.01f * v); }

// PE x-features, compile-time: cos/sin(2*pi*k/8), k = dx.
__device__ __forceinline__ constexpr float cx(int k) {
  constexpr float R = 0.70710678118654752f;
  const float t[8] = {1.f, R, 0.f, -R, -1.f, -R, 0.f, R};
  return t[k];
}
__device__ __forceinline__ constexpr float sx(int k) {
  constexpr float R = 0.70710678118654752f;
  const float t[8] = {0.f, R, 1.f, R, 0.f, -R, -1.f, -R};
  return t[k];
}

// type: 0 = bias (64ch, init y), 1 = L0 weights (256ch), 2 = hidden (256ch)
__device__ __forceinline__ void tile_desc(int t, int& c0, int& nch, int& ci0,
                                          int& type, bool& fl) {
  if (t == 0) { c0 = 0;  nch = 64;  ci0 = 0; type = 0; fl = false; return; }
  if (t == 1) { c0 = 64; nch = 256; ci0 = 0; type = 1; fl = true;  return; }
  const int u = t - 2, l = u / 17, r = u - l * 17;
  if (r == 0) { c0 = 320 + l * 4160; nch = 64; ci0 = 0; type = 0; fl = false; }
  else {
    c0 = 384 + l * 4160 + (r - 1) * 256; nch = 256; ci0 = (r - 1) * 4;
    type = 2; fl = (r == 16);
  }
}

__global__ __launch_bounds__(128, 2) void pqn(const float* __restrict__ lr,
                                              float* __restrict__ out) {
  __shared__ alignas(16) float A[2 * AHI];        // 32768 B (k-lo + k-hi planes)
  __shared__ alignas(16) float WB[2][2 * WROW];   // 4160 B

  const int tid = threadIdx.x;
  const int j   = tid & 1;
  const int pg  = (tid >> 1) & 7;      // pixel row (dy)
  const int cob = tid >> 4;            // 0..7

  // ---- swizzle: 8 siblings (same XCD) cover one 64B weight line
  const int n  = blockIdx.x;
  const int e3 = (n >> 3) & 7;
  const int P  = (n & 7) | ((n >> 6) << 3);   // 0..511
  const int jg = ((P & 3) << 3) | e3;         // 0..31 (2-j group)
  const int i  = (P >> 2) & 63;
  const int b  = (P >> 8) & 1;

  const float* __restrict__ wb =
      lr + (size_t)b * NPAR * PLANE + (size_t)(i * 64 + jg * 2);

  float fyc, fys;
  sincosf(0.78539816339744830962f * pg, &fys, &fyc);

  const int abase = pg * 8 + j * 4;    // == 4*(lane&15)
  const int wrow  = j * WROW;

  float y[64];                         // [col 0..7][k 0..7]

  auto ldstg = [&](int t, float4& stg) {
    int c0, nch, ci0, type; bool fl; tile_desc(t, c0, nch, ci0, type, fl);
    if (nch == 256) {
      const float2 va = *(const float2*)(wb + (size_t)(c0 + tid) * PLANE);
      const float2 vb = *(const float2*)(wb + (size_t)(c0 + 128 + tid) * PLANE);
      stg.x = va.x; stg.y = va.y; stg.z = vb.x; stg.w = vb.y;
    } else {
      stg.x = wb[(size_t)(c0 + (tid >> 1)) * PLANE + (tid & 1)];
    }
  };
  auto wrstg = [&](int t, int buf, const float4& stg) {
    int c0, nch, ci0, type; bool fl; tile_desc(t, c0, nch, ci0, type, fl);
    if (nch == 256) {
      WB[buf][tid]              = stg.x;
      WB[buf][WROW + tid]       = stg.y;
      WB[buf][tid + 128]        = stg.z;
      WB[buf][WROW + tid + 128] = stg.w;
    } else {
      WB[buf][(tid & 1) * WROW + (tid >> 1)] = stg.x;
    }
  };

  auto compute = [&](int t, int buf) {
    int c0, nch, ci0, type; bool fl; tile_desc(t, c0, nch, ci0, type, fl);
    const float* Wt = WB[buf];
    if (type == 0) {                   // bias: init accumulators
#pragma unroll
      for (int q = 0; q < 2; ++q) {
        const float4 w = *(const float4*)&Wt[wrow + cob * 8 + q * 4];
#pragma unroll
        for (int m = 0; m < 4; ++m) {
          const float v = ((const float*)&w)[m];
#pragma unroll
          for (int k = 0; k < 8; ++k) y[(q * 4 + m) * 8 + k] = v;
        }
      }
    } else if (type == 1) {            // L0: features [xc, xs, yc, ys]
#pragma unroll
      for (int f = 0; f < 4; ++f) {
#pragma unroll
        for (int q = 0; q < 2; ++q) {
          const float4 w = *(const float4*)&Wt[wrow + f * 64 + cob * 8 + q * 4];
#pragma unroll
          for (int m = 0; m < 4; ++m) {
            const float wv = ((const float*)&w)[m];
            const int col = q * 4 + m;
#pragma unroll
            for (int k = 0; k < 8; ++k) {
              const float a = (f == 0) ? cx(k) : (f == 1) ? sx(k)
                              : (f == 2) ? fyc : fys;
              y[col * 8 + k] = fmaf(a, wv, y[col * 8 + k]);
            }
          }
        }
      }
    } else {                           // hidden: 4 ci per tile
#pragma unroll
      for (int cl = 0; cl < 4; ++cl) {
        const int ci = ci0 + cl;
        const float4 a0 = *(const float4*)&A[ci * 64 + abase];
        const float4 a1 = *(const float4*)&A[ci * 64 + abase + AHI];
#pragma unroll
        for (int q = 0; q < 2; ++q) {
          const float4 w = *(const float4*)&Wt[wrow + cl * 64 + cob * 8 + q * 4];
#pragma unroll
          for (int m = 0; m < 4; ++m) {
            const float wv = ((const float*)&w)[m];
            const int col = q * 4 + m;
            y[col * 8 + 0] = fmaf(a0.x, wv, y[col * 8 + 0]);
            y[col * 8 + 1] = fmaf(a0.y, wv, y[col * 8 + 1]);
            y[col * 8 + 2] = fmaf(a0.z, wv, y[col * 8 + 2]);
            y[col * 8 + 3] = fmaf(a0.w, wv, y[col * 8 + 3]);
            y[col * 8 + 4] = fmaf(a1.x, wv, y[col * 8 + 4]);
            y[col * 8 + 5] = fmaf(a1.y, wv, y[col * 8 + 5]);
            y[col * 8 + 6] = fmaf(a1.z, wv, y[col * 8 + 6]);
            y[col * 8 + 7] = fmaf(a1.w, wv, y[col * 8 + 7]);
          }
        }
      }
    }
    if (fl) {                          // layer end: publish activations
      asm volatile("s_waitcnt lgkmcnt(0)" ::: "memory");
      __builtin_amdgcn_s_barrier();    // everyone's A-reads done
      __builtin_amdgcn_sched_barrier(0);
#pragma unroll
      for (int col = 0; col < 8; ++col) {
        float4 v0, v1;
        v0.x = leaky(y[col * 8 + 0]); v0.y = leaky(y[col * 8 + 1]);
        v0.z = leaky(y[col * 8 + 2]); v0.w = leaky(y[col * 8 + 3]);
        v1.x = leaky(y[col * 8 + 4]); v1.y = leaky(y[col * 8 + 5]);
        v1.z = leaky(y[col * 8 + 6]); v1.w = leaky(y[col * 8 + 7]);
        *(float4*)&A[(cob * 8 + col) * 64 + abase]       = v0;
        *(float4*)&A[(cob * 8 + col) * 64 + abase + AHI] = v1;
      }
    }
  };

  // ---- prologue: 2-deep prefetch
  float4 stgA = {}, stgB = {};
  ldstg(0, stgA);
  ldstg(1, stgB);

  for (int t = 0; t < NT; t += 2) {
    // ---- phase A: tile t -> buf 0
    wrstg(t, 0, stgA);
    asm volatile("s_waitcnt lgkmcnt(0)" ::: "memory");
    __builtin_amdgcn_s_barrier();
    __builtin_amdgcn_sched_barrier(0);
    if (t + 2 < NT) ldstg(t + 2, stgA);
    compute(t, 0);
    // ---- phase B: tile t+1 -> buf 1
    if (t + 1 < NT) {
      wrstg(t + 1, 1, stgB);
      asm volatile("s_waitcnt lgkmcnt(0)" ::: "memory");
      __builtin_amdgcn_s_barrier();
      __builtin_amdgcn_sched_barrier(0);
      if (t + 3 < NT) ldstg(t + 3, stgB);
      compute(t + 1, 1);
    }
  }

  // ---- epilogue: L4 (64 -> 3) + tanh
  asm volatile("s_waitcnt lgkmcnt(0)" ::: "memory");
  __builtin_amdgcn_s_barrier();
  __builtin_amdgcn_sched_barrier(0);

  float po[24];
#pragma unroll
  for (int m = 0; m < 24; ++m) po[m] = 0.f;
#pragma unroll
  for (int cl = 0; cl < 8; ++cl) {
    const int ci = cob * 8 + cl;
    const float4 a0 = *(const float4*)&A[ci * 64 + abase];
    const float4 a1 = *(const float4*)&A[ci * 64 + abase + AHI];
#pragma unroll
    for (int o = 0; o < 3; ++o) {
      const float w = wb[(size_t)(12803 + ci * 3 + o) * PLANE + j];
      po[o * 8 + 0] = fmaf(a0.x, w, po[o * 8 + 0]);
      po[o * 8 + 1] = fmaf(a0.y, w, po[o * 8 + 1]);
      po[o * 8 + 2] = fmaf(a0.z, w, po[o * 8 + 2]);
      po[o * 8 + 3] = fmaf(a0.w, w, po[o * 8 + 3]);
      po[o * 8 + 4] = fmaf(a1.x, w, po[o * 8 + 4]);
      po[o * 8 + 5] = fmaf(a1.y, w, po[o * 8 + 5]);
      po[o * 8 + 6] = fmaf(a1.z, w, po[o * 8 + 6]);
      po[o * 8 + 7] = fmaf(a1.w, w, po[o * 8 + 7]);
    }
  }
  asm volatile("s_waitcnt lgkmcnt(0)" ::: "memory");
  __builtin_amdgcn_s_barrier();        // all A reads done -> reuse A
  float* R = A;
#pragma unroll
  for (int m = 0; m < 24; m += 4)
    *(float4*)&R[tid * 28 + m] = *(float4*)&po[m];
  asm volatile("s_waitcnt lgkmcnt(0)" ::: "memory");
  __builtin_amdgcn_s_barrier();
  __builtin_amdgcn_sched_barrier(0);

  if (tid < 16) {                      // one (j, pg) per thread
    const int jj = tid & 1;
    const int pp = tid >> 1;
#pragma unroll
    for (int o = 0; o < 3; ++o) {
      const float bias = wb[(size_t)(12800 + o) * PLANE + jj];
      float s[8];
#pragma unroll
      for (int k = 0; k < 8; ++k) s[k] = bias;
#pragma unroll
      for (int cb = 0; cb < 8; ++cb) {
#pragma unroll
        for (int k = 0; k < 8; ++k)
          s[k] += R[(cb * 16 + tid) * 28 + o * 8 + k];
      }
      float4 v0, v1;
      v0.x = tanhf(s[0]); v0.y = tanhf(s[1]); v0.z = tanhf(s[2]); v0.w = tanhf(s[3]);
      v1.x = tanhf(s[4]); v1.y = tanhf(s[5]); v1.z = tanhf(s[6]); v1.w = tanhf(s[7]);
      float* op = out + (size_t)b * 786432 + (size_t)o * 262144 +
                  (size_t)(i * 8 + pp) * 512 + (size_t)((jg * 2 + jj) * 8);
      *(float4*)op = v0;
      *(float4*)(op + 4) = v1;
    }
  }
}

extern "C" void kernel_launch(void* const* d_in, const int* in_sizes, int n_in,
                              void* d_out, int out_size, void* d_ws, size_t ws_size,
                              hipStream_t stream) {
  (void)in_sizes; (void)n_in; (void)d_ws; (void)ws_size; (void)out_size;
  const float* lr = (const float*)d_in[1];  // d_in[0] = highres (unused by the math)
  float* out = (float*)d_out;
  hipLaunchKernelGGL(pqn, dim3(4096), dim3(128), 0, stream, lr, out);
}

// Round 8
// 376.043 us; speedup vs baseline: 1.0862x; 1.0862x over previous
//
#include <hip/hip_runtime.h>
#include <math.h>

// PixelQueryNet fused kernel, v8 (= v5 geometry + 6-deep prefetch + WROW fix).
// Per low-res cell (b,i,j): MLP 4->64->64->64->64->3 (leaky 0.01, tanh) on the
// 64 pixels of its 8x8 tile; weights from lr_params[b,c,i,j] (channel stride
// PLANE=4096 floats).
//
// Block = 256 threads = 4 cells(j) x 8 pixel-rows(pg) x 8 co-blocks(cob);
// y[8co][8px] accumulators in registers. ~70 KB LDS -> 2 blocks/CU.
// Grid = 2048; siblings n,n+8,n+16,n+24 (same XCD under %8 round-robin) take
// the four 16B j-quads of each 64B weight line -> L2 sharing, HBM ideal.
//
// R8 changes:
//  * Prefetch depth 6 (named s0..s5; NT=102=6x17). The 2-deep pipeline made
//    every tile stall on vmcnt at wrstg (slot ~1226cy >> 512cy issue demand,
//    VALUBusy pinned ~37% across R4-R7). 6 slots of lookahead covers ~5k cy.
//  * WROW 132 -> 160: weight ds_read_b128 quad starts j*40+2cob mod 32 =
//    {0,2,8,10,16,18,24,26} -> <=2-way banks (was 3-4-way at WROW=132).
//
// Activations: two unpadded planes (k0..3 / k4..7), word = ci*128 + 4*(lane&31)
// -> lane-contiguous b128, conflict-free. One raw s_barrier + lgkmcnt(0) per
// tile; global prefetch stays in flight across barriers (vmcnt counted via
// register dependencies).

static constexpr int PLANE = 4096;
static constexpr int NPAR  = 12995;
static constexpr int NT    = 102;   // 3 (L0) + 3*33 (hidden) = 6*17
static constexpr int WROW  = 160;   // words per j-row in weight tile
static constexpr int AHI   = 8192;  // word offset of the k4..7 plane

__device__ __forceinline__ float leaky(float v) { return fmaxf(v, 0.01f * v); }

// PE x-features, compile-time: cos/sin(2*pi*k/8), k = dx.
__device__ __forceinline__ constexpr float cx(int k) {
  constexpr float R = 0.70710678118654752f;
  const float t[8] = {1.f, R, 0.f, -R, -1.f, -R, 0.f, R};
  return t[k];
}
__device__ __forceinline__ constexpr float sx(int k) {
  constexpr float R = 0.70710678118654752f;
  const float t[8] = {0.f, R, 1.f, R, 0.f, -R, -1.f, -R};
  return t[k];
}

__device__ __forceinline__ void tile_desc(int t, int& c0, int& nch, int& ci0,
                                          int& type, bool& fl) {
  // type: 0=bias(init y), 1=L0 x-features, 2=L0 y-features, 3=hidden weights
  if (t == 0)      { c0 = 0;   nch = 64;  ci0 = 0; type = 0; fl = false; }
  else if (t == 1) { c0 = 64;  nch = 128; ci0 = 0; type = 1; fl = false; }
  else if (t == 2) { c0 = 192; nch = 128; ci0 = 2; type = 2; fl = true; }
  else {
    const int u = t - 3, l = u / 33, r = u - l * 33;
    if (r == 0) { c0 = 320 + l * 4160; nch = 64; ci0 = 0; type = 0; fl = false; }
    else {
      c0 = 384 + l * 4160 + (r - 1) * 128; nch = 128; ci0 = (r - 1) * 2;
      type = 3; fl = (r == 32);
    }
  }
}

__global__ __launch_bounds__(256, 2) void pqn(const float* __restrict__ lr,
                                              float* __restrict__ out) {
  __shared__ alignas(16) float A[2 * AHI];        // 65536 B (lo + hi planes)
  __shared__ alignas(16) float WB[2][4 * WROW];   // 5120 B

  const int tid = threadIdx.x;
  const int j   = tid & 3;
  const int pg  = (tid >> 2) & 7;      // pixel row (dy)
  const int cob = tid >> 5;            // 0..7

  // ---- swizzle: 4 siblings (same XCD) cover one 64B weight line
  const int n  = blockIdx.x;
  const int e2 = (n >> 3) & 3;
  const int P  = (n & 7) | ((n >> 5) << 3);   // 0..511
  const int jg = ((P & 3) << 2) | e2;         // 0..15 (4-j group)
  const int i  = (P >> 2) & 63;
  const int b  = (P >> 8) & 1;

  const float* __restrict__ wb =
      lr + (size_t)b * NPAR * PLANE + (size_t)(i * 64 + jg * 4);

  float fyc, fys;
  sincosf(0.78539816339744830962f * pg, &fys, &fyc);

  const int abase = pg * 16 + j * 4;   // == (lane&31)*4 : lane-contiguous
  const int wrow  = j * WROW;

  float y[64];                         // [col 0..7][k 0..7]

  auto ldstg = [&](int t, float4& stg) {
    int c0, nch, ci0, type; bool fl; tile_desc(t, c0, nch, ci0, type, fl);
    if (tid < nch) stg = *(const float4*)(wb + (size_t)(c0 + tid) * PLANE);
  };
  auto wrstg = [&](int t, int buf, const float4& stg) {
    int c0, nch, ci0, type; bool fl; tile_desc(t, c0, nch, ci0, type, fl);
    if (tid < nch) {
#pragma unroll
      for (int jj = 0; jj < 4; ++jj)
        WB[buf][jj * WROW + tid] = ((const float*)&stg)[jj];
    }
  };

  auto compute = [&](int t, int buf) {
    int c0, nch, ci0, type; bool fl;
    tile_desc(t, c0, nch, ci0, type, fl);
    const float* Wt = WB[buf];
    if (type == 0) {                   // bias: init accumulators
#pragma unroll
      for (int q = 0; q < 2; ++q) {
        const float4 w = *(const float4*)&Wt[wrow + cob * 8 + q * 4];
#pragma unroll
        for (int m = 0; m < 4; ++m) {
          const float v = ((const float*)&w)[m];
#pragma unroll
          for (int k = 0; k < 8; ++k) y[(q * 4 + m) * 8 + k] = v;
        }
      }
    } else if (type == 1) {            // L0 x-features (compile-time a)
#pragma unroll
      for (int cl = 0; cl < 2; ++cl) {
#pragma unroll
        for (int q = 0; q < 2; ++q) {
          const float4 w = *(const float4*)&Wt[wrow + cl * 64 + cob * 8 + q * 4];
#pragma unroll
          for (int m = 0; m < 4; ++m) {
            const float wv = ((const float*)&w)[m];
            const int col = q * 4 + m;
#pragma unroll
            for (int k = 0; k < 8; ++k)
              y[col * 8 + k] = fmaf(cl ? sx(k) : cx(k), wv, y[col * 8 + k]);
          }
        }
      }
    } else if (type == 2) {            // L0 y-features (uniform over k)
#pragma unroll
      for (int cl = 0; cl < 2; ++cl) {
        const float a = cl ? fys : fyc;
#pragma unroll
        for (int q = 0; q < 2; ++q) {
          const float4 w = *(const float4*)&Wt[wrow + cl * 64 + cob * 8 + q * 4];
#pragma unroll
          for (int m = 0; m < 4; ++m) {
            const float wv = ((const float*)&w)[m];
            const int col = q * 4 + m;
#pragma unroll
            for (int k = 0; k < 8; ++k)
              y[col * 8 + k] = fmaf(a, wv, y[col * 8 + k]);
          }
        }
      }
    } else {                           // hidden: 2 ci per tile
#pragma unroll
      for (int cl = 0; cl < 2; ++cl) {
        const int ci = ci0 + cl;
        const float4 a0 = *(const float4*)&A[ci * 128 + abase];         // k0..3
        const float4 a1 = *(const float4*)&A[ci * 128 + abase + AHI];   // k4..7
#pragma unroll
        for (int q = 0; q < 2; ++q) {
          const float4 w = *(const float4*)&Wt[wrow + cl * 64 + cob * 8 + q * 4];
#pragma unroll
          for (int m = 0; m < 4; ++m) {
            const float wv = ((const float*)&w)[m];
            const int col = q * 4 + m;
            y[col * 8 + 0] = fmaf(a0.x, wv, y[col * 8 + 0]);
            y[col * 8 + 1] = fmaf(a0.y, wv, y[col * 8 + 1]);
            y[col * 8 + 2] = fmaf(a0.z, wv, y[col * 8 + 2]);
            y[col * 8 + 3] = fmaf(a0.w, wv, y[col * 8 + 3]);
            y[col * 8 + 4] = fmaf(a1.x, wv, y[col * 8 + 4]);
            y[col * 8 + 5] = fmaf(a1.y, wv, y[col * 8 + 5]);
            y[col * 8 + 6] = fmaf(a1.z, wv, y[col * 8 + 6]);
            y[col * 8 + 7] = fmaf(a1.w, wv, y[col * 8 + 7]);
          }
        }
      }
    }
    if (fl) {                          // layer end: publish activations
      asm volatile("s_waitcnt lgkmcnt(0)" ::: "memory");
      __builtin_amdgcn_s_barrier();    // everyone's A-reads done
      __builtin_amdgcn_sched_barrier(0);
#pragma unroll
      for (int col = 0; col < 8; ++col) {
        float4 v0, v1;
        v0.x = leaky(y[col * 8 + 0]); v0.y = leaky(y[col * 8 + 1]);
        v0.z = leaky(y[col * 8 + 2]); v0.w = leaky(y[col * 8 + 3]);
        v1.x = leaky(y[col * 8 + 4]); v1.y = leaky(y[col * 8 + 5]);
        v1.z = leaky(y[col * 8 + 6]); v1.w = leaky(y[col * 8 + 7]);
        *(float4*)&A[(cob * 8 + col) * 128 + abase]       = v0;
        *(float4*)&A[(cob * 8 + col) * 128 + abase + AHI] = v1;
      }
    }
  };

  // ---- prologue: 6-deep prefetch
  float4 s0 = {}, s1 = {}, s2 = {}, s3 = {}, s4 = {}, s5 = {};
  ldstg(0, s0); ldstg(1, s1); ldstg(2, s2);
  ldstg(3, s3); ldstg(4, s4); ldstg(5, s5);

#define PHASE(T, SREG, BUF)                                   \
  wrstg((T), (BUF), SREG);                                    \
  asm volatile("s_waitcnt lgkmcnt(0)" ::: "memory");          \
  __builtin_amdgcn_s_barrier();                               \
  __builtin_amdgcn_sched_barrier(0);                          \
  if ((T) + 6 < NT) ldstg((T) + 6, SREG);                     \
  compute((T), (BUF));

  for (int t = 0; t < NT; t += 6) {    // 17 full groups of 6
    PHASE(t,     s0, 0)
    PHASE(t + 1, s1, 1)
    PHASE(t + 2, s2, 0)
    PHASE(t + 3, s3, 1)
    PHASE(t + 4, s4, 0)
    PHASE(t + 5, s5, 1)
  }
#undef PHASE

  // ---- epilogue: L4 (64 -> 3) + tanh
  asm volatile("s_waitcnt lgkmcnt(0)" ::: "memory");
  __builtin_amdgcn_s_barrier();
  __builtin_amdgcn_sched_barrier(0);

  float po[24];
#pragma unroll
  for (int m = 0; m < 24; ++m) po[m] = 0.f;
#pragma unroll
  for (int cl = 0; cl < 8; ++cl) {
    const int ci = cob * 8 + cl;
    const float4 a0 = *(const float4*)&A[ci * 128 + abase];
    const float4 a1 = *(const float4*)&A[ci * 128 + abase + AHI];
#pragma unroll
    for (int o = 0; o < 3; ++o) {
      const float w = wb[(size_t)(12803 + ci * 3 + o) * PLANE + j];
      po[o * 8 + 0] = fmaf(a0.x, w, po[o * 8 + 0]);
      po[o * 8 + 1] = fmaf(a0.y, w, po[o * 8 + 1]);
      po[o * 8 + 2] = fmaf(a0.z, w, po[o * 8 + 2]);
      po[o * 8 + 3] = fmaf(a0.w, w, po[o * 8 + 3]);
      po[o * 8 + 4] = fmaf(a1.x, w, po[o * 8 + 4]);
      po[o * 8 + 5] = fmaf(a1.y, w, po[o * 8 + 5]);
      po[o * 8 + 6] = fmaf(a1.z, w, po[o * 8 + 6]);
      po[o * 8 + 7] = fmaf(a1.w, w, po[o * 8 + 7]);
    }
  }
  asm volatile("s_waitcnt lgkmcnt(0)" ::: "memory");
  __builtin_amdgcn_s_barrier();        // all A reads done -> reuse A
  float* R = A;
#pragma unroll
  for (int m = 0; m < 24; m += 4)
    *(float4*)&R[tid * 28 + m] = *(float4*)&po[m];
  asm volatile("s_waitcnt lgkmcnt(0)" ::: "memory");
  __builtin_amdgcn_s_barrier();
  __builtin_amdgcn_sched_barrier(0);

  if (cob == 0) {                      // tid < 32: one (j, pg) per thread
#pragma unroll
    for (int o = 0; o < 3; ++o) {
      const float bias = wb[(size_t)(12800 + o) * PLANE + j];
      float s[8];
#pragma unroll
      for (int k = 0; k < 8; ++k) s[k] = bias;
#pragma unroll
      for (int cb = 0; cb < 8; ++cb) {
#pragma unroll
        for (int k = 0; k < 8; ++k)
          s[k] += R[(cb * 32 + tid) * 28 + o * 8 + k];
      }
      float4 v0, v1;
      v0.x = tanhf(s[0]); v0.y = tanhf(s[1]); v0.z = tanhf(s[2]); v0.w = tanhf(s[3]);
      v1.x = tanhf(s[4]); v1.y = tanhf(s[5]); v1.z = tanhf(s[6]); v1.w = tanhf(s[7]);
      float* op = out + (size_t)b * 786432 + (size_t)o * 262144 +
                  (size_t)(i * 8 + pg) * 512 + (size_t)((jg * 4 + j) * 8);
      *(float4*)op = v0;
      *(float4*)(op + 4) = v1;
    }
  }
}

extern "C" void kernel_launch(void* const* d_in, const int* in_sizes, int n_in,
                              void* d_out, int out_size, void* d_ws, size_t ws_size,
                              hipStream_t stream) {
  (void)in_sizes; (void)n_in; (void)d_ws; (void)ws_size; (void)out_size;
  const float* lr = (const float*)d_in[1];  // d_in[0] = highres (unused by the math)
  float* out = (float*)d_out;
  hipLaunchKernelGGL(pqn, dim3(2048), dim3(256), 0, stream, lr, out);
}